// Round 17
// baseline (893.269 us; speedup 1.0000x reference)
//
#include <hip/hip_runtime.h>
#include <math.h>

// BiometricLSTM: 2-layer LSTM, B=512, T=2048, I=3, H=64, fp32 in/out. Output = final h2 (B,64).
//
// R34: R33 (best, 829.4 us) + post-MFMA chain minimization (enabled by R33's
// "only reg 0 matters" layout):
//  (1) Split accumulators with SCALAR merge (clean R23 retry): acc0=mfma(a0,w0,C0),
//      acc1=mfma(a1,w1,Z) complete in parallel; merge = acc0[c][0]+acc1[c][0]
//      (one add — R23's failure was the 2-sel4-per-merge tax, eliminated by R33).
//      Saves one MFMA dep-latency (~20-30cy) on both roles' chains.
//  (2) Bias+xp (L0) / bias+qp (L1) folded into MFMA C element 0 (regs 1-3 are
//      discarded replicas): C0={cb+xp,0,0,0}. L0's bias rides the xp fma tail
//      (same op count); L1 adds 4 window-adds. Post-MFMA chain is now
//      {merge-add -> activation} only.
//  Summation order changes -> absmax may drift a ulp from 4.88e-4.
// R33 recap (all kept): seq=row>>2 replication (A read (l16>>2)*HSTR) -> all 4
// C/D regs of lane = seq quad, no sel4 anywhere; g-first MFMA order; fused tanh
// muls; log2e-prescaled weights (bare v_exp2); split waves L0=Whh0 8(x2) MFMA /
// L1=Whh1+Wih1 lag-2 in order {reads, qp, gates, pI, tail, write}; pI in regs
// accQ[2][4] (write@sub, read@sub^1); LDS 2560B, 0 conflicts; unroll-2
// compile-time parity; HSTR=80; x prefetch depth-1; lds_barrier (lgkmcnt-only);
// setprio(1) on L0; f16 weights/h + f32 accum.
// Refuted ledger: vmcnt drain (R24), x latency (R27), prio (R29), LDS rebalance
// (R28), pI-after-write (R31), gate-order (R32 neutral).
// Parities: h1[t]@t&1; h2[t]@t&1; accQ write@sub / read@sub^1.

typedef _Float16 half8 __attribute__((ext_vector_type(8)));
typedef float    f32x4 __attribute__((ext_vector_type(4)));

constexpr int TT = 2048;
constexpr int HSTR = 80;   // h row stride in halves (160 B)

#define LOG2E  1.44269504088896340736f
#define LOG2E2 2.88539008177792681472f

// y = x*log2e applied upstream: sigmoid(x) = 1/(1+2^-y)
__device__ __forceinline__ float sig_p(float y) {
    return __builtin_amdgcn_rcpf(1.0f + __builtin_amdgcn_exp2f(-y));
}
// y = x*2log2e applied upstream: r = 1/(2^y+1); tanh(x) = 1 - 2r
__device__ __forceinline__ float tanh_r(float y) {
    return __builtin_amdgcn_rcpf(__builtin_amdgcn_exp2f(y) + 1.0f);
}

// Barrier with LDS-only drain: s_waitcnt lgkmcnt(0) + s_barrier.
// Does NOT drain vmcnt — in-flight global x-prefetch loads stay in flight.
__device__ __forceinline__ void lds_barrier() {
    __builtin_amdgcn_sched_barrier(0);
    asm volatile("s_waitcnt lgkmcnt(0)" ::: "memory");
    __builtin_amdgcn_s_barrier();
    __builtin_amdgcn_sched_barrier(0);
}

__global__ __launch_bounds__(512) void lstm2_fused(
    const float* __restrict__ x,
    const float* __restrict__ Wih0, const float* __restrict__ Whh0,
    const float* __restrict__ bih0, const float* __restrict__ bhh0,
    const float* __restrict__ Wih1, const float* __restrict__ Whh1,
    const float* __restrict__ bih1, const float* __restrict__ bhh1,
    float* __restrict__ out)
{
    __shared__ __align__(16) _Float16 h1a[2][4 * HSTR];   // [parity][seq*HSTR + elem]
    __shared__ __align__(16) _Float16 h2a[2][4 * HSTR];

    const int tid  = threadIdx.x;
    const int lane = tid & 63;
    const int wid  = tid >> 6;
    const int quad = lane >> 4;
    const int l16  = lane & 15;
    const bool isL1 = (wid >= 4);
    const int col  = (wid & 3) * 16 + l16;   // gate-elem column this lane owns per class

    // ---- zero h double-buffers ----
    for (int i = tid; i < 2 * 4 * HSTR; i += 512) {
        ((_Float16*)h1a)[i] = (_Float16)0.0f;
        ((_Float16*)h2a)[i] = (_Float16)0.0f;
    }

    // ---- weights (B-frags, f16), log2e-prescaled per gate class ----
    // class c: 0=i 1=f 2=g 3=o; scale = log2e (sigmoid) or 2*log2e (tanh g)
    half8 wA[4][2];      // L0 waves: Whh0 | L1 waves: Whh1
    half8 wB[4][2];      // L1 waves only: Wih1
    float cb[4];         // scalar bias (prescaled) — folded into C elem 0
    float wxa[4], wxb[4], wxc[4];            // L0 only (prescaled)
    #pragma unroll
    for (int c = 0; c < 4; ++c) {
        const int row = c * 64 + col;
        const float sc = (c == 2) ? LOG2E2 : LOG2E;
        if (!isL1) {
            #pragma unroll
            for (int f = 0; f < 2; ++f) {
                const float* p = Whh0 + (size_t)row * 64 + f * 32 + quad * 8;
                half8 h;
                #pragma unroll
                for (int u = 0; u < 8; ++u) h[u] = (_Float16)(p[u] * sc);
                wA[c][f] = h;
            }
            cb[c] = (bih0[row] + bhh0[row]) * sc;
            wxa[c] = Wih0[row*3+0] * sc;
            wxb[c] = Wih0[row*3+1] * sc;
            wxc[c] = Wih0[row*3+2] * sc;
        } else {
            #pragma unroll
            for (int f = 0; f < 2; ++f) {
                const float* p = Whh1 + (size_t)row * 64 + f * 32 + quad * 8;
                half8 h;
                #pragma unroll
                for (int u = 0; u < 8; ++u) h[u] = (_Float16)(p[u] * sc);
                wA[c][f] = h;
                const float* q = Wih1 + (size_t)row * 64 + f * 32 + quad * 8;
                half8 g;
                #pragma unroll
                for (int u = 0; u < 8; ++u) g[u] = (_Float16)(q[u] * sc);
                wB[c][f] = g;
            }
            cb[c] = (bih1[row] + bhh1[row]) * sc;
        }
    }

    // ---- x prefetch (L0 waves), depth 1: this lane's seq = quad ----
    const float* xq = x + (size_t)(blockIdx.x * 4 + quad) * TT * 3;
    float xn0 = 0.f, xn1 = 0.f, xn2 = 0.f;
    if (!isL1) { xn0 = xq[0]; xn1 = xq[1]; xn2 = xq[2]; }

    const f32x4 Z = {0.f, 0.f, 0.f, 0.f};
    float cst = 0.0f;    // cell state (layer per role, seq=quad, elem=col)

    // L1: pI double-buffer in registers; accQ[sub] written at parity sub,
    // read at sub^1. Indices are compile-time after the unroll (rule #20).
    f32x4 accQ[2][4];
    #pragma unroll
    for (int s = 0; s < 2; ++s)
        #pragma unroll
        for (int c = 0; c < 4; ++c) accQ[s][c] = Z;

    // protect the h1-recurrence wave at issue-contention points (neutral, free)
    if (!isL1) __builtin_amdgcn_s_setprio(1);

    __syncthreads();   // init barrier: full drain fine here (once)

    // MFMA issue order: g first (longest post-MFMA chain), i, f, o.
    const int ORD[4] = {2, 0, 1, 3};

    // iter it = 0 .. TT+1 in unrolled pairs (cur/prev compile-time).
    // L0: step it (it<TT).  L1: gates for step it-2 (it>=2) + pI(it-1) (1<=it<=TT).
    // ONE lds_barrier per iteration.
    for (int bt = 0; bt <= TT + 1; bt += 2) {
        #pragma unroll
        for (int sub = 0; sub < 2; ++sub) {
            const int it   = bt + sub;
            const int cur  = sub;        // bt even => it&1 == sub
            const int prev = sub ^ 1;

            if (!isL1) {
                if (it < TT) {
                    // A-frags: h1[it-1] (parity prev), seq = l16>>2 replication
                    const _Float16* hb = h1a[prev] + (l16 >> 2) * HSTR + quad * 8;
                    half8 a0 = *(const half8*)hb;
                    half8 a1 = *(const half8*)(hb + 32);

                    // read window: xps[c] = bias + x-projection (bias folded
                    // into the fma tail — same op count as before).
                    const float x0 = xn0, x1 = xn1, x2 = xn2;
                    float xps0 = fmaf(wxa[0], x0, fmaf(wxb[0], x1, fmaf(wxc[0], x2, cb[0])));
                    float xps1 = fmaf(wxa[1], x0, fmaf(wxb[1], x1, fmaf(wxc[1], x2, cb[1])));
                    float xps2 = fmaf(wxa[2], x0, fmaf(wxb[2], x1, fmaf(wxc[2], x2, cb[2])));
                    float xps3 = fmaf(wxa[3], x0, fmaf(wxb[3], x1, fmaf(wxc[3], x2, cb[3])));
                    const int nt = (it + 1 < TT) ? it + 1 : TT - 1;
                    const float* np = xq + nt * 3;
                    xn0 = np[0]; xn1 = np[1]; xn2 = np[2];
                    // C operands: elem 0 = bias+xp (regs 1-3 are discarded)
                    f32x4 c0_0 = {xps0, 0.f, 0.f, 0.f};
                    f32x4 c0_1 = {xps1, 0.f, 0.f, 0.f};
                    f32x4 c0_2 = {xps2, 0.f, 0.f, 0.f};
                    f32x4 c0_3 = {xps3, 0.f, 0.f, 0.f};

                    // Split accumulators: a0/a1 halves complete in PARALLEL.
                    f32x4 acc0[4], acc1[4];
                    acc0[2] = __builtin_amdgcn_mfma_f32_16x16x32_f16(a0, wA[2][0], c0_2, 0, 0, 0);
                    acc1[2] = __builtin_amdgcn_mfma_f32_16x16x32_f16(a1, wA[2][1], Z,    0, 0, 0);
                    acc0[0] = __builtin_amdgcn_mfma_f32_16x16x32_f16(a0, wA[0][0], c0_0, 0, 0, 0);
                    acc1[0] = __builtin_amdgcn_mfma_f32_16x16x32_f16(a1, wA[0][1], Z,    0, 0, 0);
                    acc0[1] = __builtin_amdgcn_mfma_f32_16x16x32_f16(a0, wA[1][0], c0_1, 0, 0, 0);
                    acc1[1] = __builtin_amdgcn_mfma_f32_16x16x32_f16(a1, wA[1][1], Z,    0, 0, 0);
                    acc0[3] = __builtin_amdgcn_mfma_f32_16x16x32_f16(a0, wA[3][0], c0_3, 0, 0, 0);
                    acc1[3] = __builtin_amdgcn_mfma_f32_16x16x32_f16(a1, wA[3][1], Z,    0, 0, 0);

                    // tail: single merge-add per gate, then activation.
                    float pg = acc0[2][0] + acc1[2][0];
                    float pi = acc0[0][0] + acc1[0][0];
                    float pf = acc0[1][0] + acc1[1][0];
                    float po = acc0[3][0] + acc1[3][0];
                    float rg = tanh_r(pg);
                    float iv = sig_p(pi);
                    float fv = sig_p(pf), ov = sig_p(po);
                    float m2iv = -2.0f * iv;                 // off-chain
                    float igv = fmaf(m2iv, rg, iv);          // iv*tanh(g), 1 dep
                    cst = fmaf(fv, cst, igv);
                    float m2ov = -2.0f * ov;                 // off-chain (c runs)
                    float rh = tanh_r(cst * LOG2E2);
                    float hv = fmaf(m2ov, rh, ov);           // ov*tanh(c), 1 dep
                    h1a[cur][quad * HSTR + col] = (_Float16)hv;   // h1[it]
                }
            } else {
                const bool doG = (it >= 2);             // gates for step it-2
                const bool doQ = (it >= 1 && it <= TT); // pI(it-1) for next iter

                // ds_reads first (both frag sets issue together)
                half8 a2, a3, b0, b1;
                if (doG) {
                    const _Float16* hb2 = h2a[prev] + (l16 >> 2) * HSTR + quad * 8;
                    a2 = *(const half8*)hb2;
                    a3 = *(const half8*)(hb2 + 32);
                }
                if (doQ) {
                    const _Float16* hb1 = h1a[prev] + (l16 >> 2) * HSTR + quad * 8;
                    b0 = *(const half8*)hb1;
                    b1 = *(const half8*)(hb1 + 32);
                }

                // read window: C elem 0 = bias + pI(it-2) partial (reg read)
                f32x4 c0_0, c0_1, c0_2, c0_3;
                if (doG) {
                    c0_0 = f32x4{cb[0] + accQ[prev][0][0], 0.f, 0.f, 0.f};
                    c0_1 = f32x4{cb[1] + accQ[prev][1][0], 0.f, 0.f, 0.f};
                    c0_2 = f32x4{cb[2] + accQ[prev][2][0], 0.f, 0.f, 0.f};
                    c0_3 = f32x4{cb[3] + accQ[prev][3][0], 0.f, 0.f, 0.f};
                }

                // Split accumulators, g-first (gates -> pI -> tail -> write).
                f32x4 acc0[4], acc1[4];
                if (doG) {
                    acc0[2] = __builtin_amdgcn_mfma_f32_16x16x32_f16(a2, wA[2][0], c0_2, 0, 0, 0);
                    acc1[2] = __builtin_amdgcn_mfma_f32_16x16x32_f16(a3, wA[2][1], Z,    0, 0, 0);
                    acc0[0] = __builtin_amdgcn_mfma_f32_16x16x32_f16(a2, wA[0][0], c0_0, 0, 0, 0);
                    acc1[0] = __builtin_amdgcn_mfma_f32_16x16x32_f16(a3, wA[0][1], Z,    0, 0, 0);
                    acc0[1] = __builtin_amdgcn_mfma_f32_16x16x32_f16(a2, wA[1][0], c0_1, 0, 0, 0);
                    acc1[1] = __builtin_amdgcn_mfma_f32_16x16x32_f16(a3, wA[1][1], Z,    0, 0, 0);
                    acc0[3] = __builtin_amdgcn_mfma_f32_16x16x32_f16(a2, wA[3][0], c0_3, 0, 0, 0);
                    acc1[3] = __builtin_amdgcn_mfma_f32_16x16x32_f16(a3, wA[3][1], Z,    0, 0, 0);
                }
                // pI(it-1) = Wih1 . h1[it-1] -> accQ[sub] (z-chained, off-crit;
                // issues behind gates, hides under the tail's acc wait).
                if (doQ) {
                    #pragma unroll
                    for (int c = 0; c < 4; ++c) {
                        f32x4 z = Z;
                        z = __builtin_amdgcn_mfma_f32_16x16x32_f16(b0, wB[c][0], z, 0, 0, 0);
                        z = __builtin_amdgcn_mfma_f32_16x16x32_f16(b1, wB[c][1], z, 0, 0, 0);
                        accQ[sub][c] = z;
                    }
                }

                if (doG) {
                    float pg = acc0[2][0] + acc1[2][0];
                    float pi = acc0[0][0] + acc1[0][0];
                    float pf = acc0[1][0] + acc1[1][0];
                    float po = acc0[3][0] + acc1[3][0];
                    float rg = tanh_r(pg);
                    float iv = sig_p(pi);
                    float fv = sig_p(pf), ov = sig_p(po);
                    float m2iv = -2.0f * iv;
                    float igv = fmaf(m2iv, rg, iv);
                    cst = fmaf(fv, cst, igv);
                    float m2ov = -2.0f * ov;
                    float rh = tanh_r(cst * LOG2E2);
                    float hv = fmaf(m2ov, rh, ov);
                    h2a[cur][quad * HSTR + col] = (_Float16)hv;   // h2[it-2]
                    if (it == TT + 1)
                        out[(size_t)(blockIdx.x * 4 + quad) * 64 + col] = hv;
                }
            }
            lds_barrier();   // LDS-only drain; x prefetch stays in flight
        }
    }
}

extern "C" void kernel_launch(void* const* d_in, const int* in_sizes, int n_in,
                              void* d_out, int out_size, void* d_ws, size_t ws_size,
                              hipStream_t stream) {
    const float* x    = (const float*)d_in[0];
    const float* Wih0 = (const float*)d_in[1];
    const float* Whh0 = (const float*)d_in[2];
    const float* bih0 = (const float*)d_in[3];
    const float* bhh0 = (const float*)d_in[4];
    const float* Wih1 = (const float*)d_in[5];
    const float* Whh1 = (const float*)d_in[6];
    const float* bih1 = (const float*)d_in[7];
    const float* bhh1 = (const float*)d_in[8];
    float* out = (float*)d_out;

    // 512 sequences / 4 per block = 128 blocks; 512 threads (8 waves, 2/SIMD).
    lstm2_fused<<<128, 512, 0, stream>>>(x, Wih0, Whh0, bih0, bhh0,
                                         Wih1, Whh1, bih1, bhh1, out);
}

// Round 19
// 892.920 us; speedup vs baseline: 1.0004x; 1.0004x over previous
//
#include <hip/hip_runtime.h>
#include <math.h>

// BiometricLSTM: 2-layer LSTM, B=512, T=2048, I=3, H=64, fp32 in/out. Output = final h2 (B,64).
//
// R36 == R35 resubmitted verbatim (GPUAcquisitionTimeout; split-acc hypothesis
// still unmeasured — do not stack changes).
//
// R35: R33 (best, 829.4 us; R34 REVERTED: +7.7%, per-iter C-vector construction
// movs + doubled acc defs outweighed the saved dep) + ONE variable: split
// accumulators with PRE-BUILT C operands.
//   acc0[c] = mfma(a0, wA[c][0], cbias[c])   // cbias f32x4 built once at init
//   acc1[c] = mfma(a1, wA[c][1], Z)          // both complete in PARALLEL
//   tail: p = (acc0[c][0] + acc1[c][0]) + xp // +1 scalar add, -1 MFMA dep (~20cy)
// Third attempt at this idea, each confound removed in turn: R23 failed on
// sel4-merge tax (gone since R33); R34 failed on per-iter C construction
// (gone here — no C is built per iteration). pI stays z-chained (off-critical).
// Merge rounds once at the explicit add -> absmax may move +-1 ulp.
// R33 recap (all kept): seq=row>>2 replication -> all 4 C/D regs = seq quad,
// no sel4; g-first MFMA order; fused tanh muls (m2iv/m2ov); log2e-prescaled
// weights (bare v_exp2); split waves L0=Whh0 / L1=Whh1+Wih1 lag-2 in order
// {reads, qp, gates, pI, tail, write}; pI in regs accQ[2][4] (write@sub,
// read@sub^1); LDS 2560B, 0 conflicts; unroll-2 compile-time parity; HSTR=80;
// x prefetch depth-1; lds_barrier (lgkmcnt-only); setprio(1) on L0;
// f16 weights/h + f32 accum.
// Refuted ledger: vmcnt drain (R24), x latency (R27), prio (R29), LDS
// rebalance (R28), pI-after-write (R31), gate-order (R32), C-fold (R34).
// Parities: h1[t]@t&1; h2[t]@t&1; accQ write@sub / read@sub^1.

typedef _Float16 half8 __attribute__((ext_vector_type(8)));
typedef float    f32x4 __attribute__((ext_vector_type(4)));

constexpr int TT = 2048;
constexpr int HSTR = 80;   // h row stride in halves (160 B)

#define LOG2E  1.44269504088896340736f
#define LOG2E2 2.88539008177792681472f

// y = x*log2e applied upstream: sigmoid(x) = 1/(1+2^-y)
__device__ __forceinline__ float sig_p(float y) {
    return __builtin_amdgcn_rcpf(1.0f + __builtin_amdgcn_exp2f(-y));
}
// y = x*2log2e applied upstream: r = 1/(2^y+1); tanh(x) = 1 - 2r
__device__ __forceinline__ float tanh_r(float y) {
    return __builtin_amdgcn_rcpf(__builtin_amdgcn_exp2f(y) + 1.0f);
}

// Barrier with LDS-only drain: s_waitcnt lgkmcnt(0) + s_barrier.
// Does NOT drain vmcnt — in-flight global x-prefetch loads stay in flight.
__device__ __forceinline__ void lds_barrier() {
    __builtin_amdgcn_sched_barrier(0);
    asm volatile("s_waitcnt lgkmcnt(0)" ::: "memory");
    __builtin_amdgcn_s_barrier();
    __builtin_amdgcn_sched_barrier(0);
}

__global__ __launch_bounds__(512) void lstm2_fused(
    const float* __restrict__ x,
    const float* __restrict__ Wih0, const float* __restrict__ Whh0,
    const float* __restrict__ bih0, const float* __restrict__ bhh0,
    const float* __restrict__ Wih1, const float* __restrict__ Whh1,
    const float* __restrict__ bih1, const float* __restrict__ bhh1,
    float* __restrict__ out)
{
    __shared__ __align__(16) _Float16 h1a[2][4 * HSTR];   // [parity][seq*HSTR + elem]
    __shared__ __align__(16) _Float16 h2a[2][4 * HSTR];

    const int tid  = threadIdx.x;
    const int lane = tid & 63;
    const int wid  = tid >> 6;
    const int quad = lane >> 4;
    const int l16  = lane & 15;
    const bool isL1 = (wid >= 4);
    const int col  = (wid & 3) * 16 + l16;   // gate-elem column this lane owns per class

    // ---- zero h double-buffers ----
    for (int i = tid; i < 2 * 4 * HSTR; i += 512) {
        ((_Float16*)h1a)[i] = (_Float16)0.0f;
        ((_Float16*)h2a)[i] = (_Float16)0.0f;
    }

    // ---- weights (B-frags, f16), log2e-prescaled per gate class ----
    // class c: 0=i 1=f 2=g 3=o; scale = log2e (sigmoid) or 2*log2e (tanh g)
    half8 wA[4][2];      // L0 waves: Whh0 | L1 waves: Whh1
    half8 wB[4][2];      // L1 waves only: Wih1
    f32x4 cbias[4];      // bias splat (prescaled), MFMA C-init — built ONCE
    float wxa[4], wxb[4], wxc[4];            // L0 only (prescaled)
    #pragma unroll
    for (int c = 0; c < 4; ++c) {
        const int row = c * 64 + col;
        const float sc = (c == 2) ? LOG2E2 : LOG2E;
        if (!isL1) {
            #pragma unroll
            for (int f = 0; f < 2; ++f) {
                const float* p = Whh0 + (size_t)row * 64 + f * 32 + quad * 8;
                half8 h;
                #pragma unroll
                for (int u = 0; u < 8; ++u) h[u] = (_Float16)(p[u] * sc);
                wA[c][f] = h;
            }
            const float b = (bih0[row] + bhh0[row]) * sc;
            cbias[c] = f32x4{b, b, b, b};
            wxa[c] = Wih0[row*3+0] * sc;
            wxb[c] = Wih0[row*3+1] * sc;
            wxc[c] = Wih0[row*3+2] * sc;
        } else {
            #pragma unroll
            for (int f = 0; f < 2; ++f) {
                const float* p = Whh1 + (size_t)row * 64 + f * 32 + quad * 8;
                half8 h;
                #pragma unroll
                for (int u = 0; u < 8; ++u) h[u] = (_Float16)(p[u] * sc);
                wA[c][f] = h;
                const float* q = Wih1 + (size_t)row * 64 + f * 32 + quad * 8;
                half8 g;
                #pragma unroll
                for (int u = 0; u < 8; ++u) g[u] = (_Float16)(q[u] * sc);
                wB[c][f] = g;
            }
            const float b = (bih1[row] + bhh1[row]) * sc;
            cbias[c] = f32x4{b, b, b, b};
        }
    }

    // ---- x prefetch (L0 waves), depth 1: this lane's seq = quad ----
    const float* xq = x + (size_t)(blockIdx.x * 4 + quad) * TT * 3;
    float xn0 = 0.f, xn1 = 0.f, xn2 = 0.f;
    if (!isL1) { xn0 = xq[0]; xn1 = xq[1]; xn2 = xq[2]; }

    const f32x4 Z = {0.f, 0.f, 0.f, 0.f};
    float cst = 0.0f;    // cell state (layer per role, seq=quad, elem=col)

    // L1: pI double-buffer in registers; accQ[sub] written at parity sub,
    // read at sub^1. Indices are compile-time after the unroll (rule #20).
    f32x4 accQ[2][4];
    #pragma unroll
    for (int s = 0; s < 2; ++s)
        #pragma unroll
        for (int c = 0; c < 4; ++c) accQ[s][c] = Z;

    // protect the h1-recurrence wave at issue-contention points (neutral, free)
    if (!isL1) __builtin_amdgcn_s_setprio(1);

    __syncthreads();   // init barrier: full drain fine here (once)

    // iter it = 0 .. TT+1 in unrolled pairs (cur/prev compile-time).
    // L0: step it (it<TT).  L1: gates for step it-2 (it>=2) + pI(it-1) (1<=it<=TT).
    // ONE lds_barrier per iteration.
    for (int bt = 0; bt <= TT + 1; bt += 2) {
        #pragma unroll
        for (int sub = 0; sub < 2; ++sub) {
            const int it   = bt + sub;
            const int cur  = sub;        // bt even => it&1 == sub
            const int prev = sub ^ 1;

            if (!isL1) {
                if (it < TT) {
                    // A-frags: h1[it-1] (parity prev), seq = l16>>2 replication
                    const _Float16* hb = h1a[prev] + (l16 >> 2) * HSTR + quad * 8;
                    half8 a0 = *(const half8*)hb;
                    half8 a1 = *(const half8*)(hb + 32);

                    // x-projection (prescaled): fills the ds_read window.
                    const float x0 = xn0, x1 = xn1, x2 = xn2;
                    float xp0 = fmaf(wxa[0], x0, fmaf(wxb[0], x1, wxc[0] * x2));
                    float xp1 = fmaf(wxa[1], x0, fmaf(wxb[1], x1, wxc[1] * x2));
                    float xp2 = fmaf(wxa[2], x0, fmaf(wxb[2], x1, wxc[2] * x2));
                    float xp3 = fmaf(wxa[3], x0, fmaf(wxb[3], x1, wxc[3] * x2));
                    const int nt = (it + 1 < TT) ? it + 1 : TT - 1;
                    const float* np = xq + nt * 3;
                    xn0 = np[0]; xn1 = np[1]; xn2 = np[2];

                    // Split accumulators, g-first: both halves in PARALLEL.
                    // C operands pre-built (cbias at init, Z const) — no
                    // per-iteration vector construction (R34's failure mode).
                    f32x4 acc0[4], acc1[4];
                    acc0[2] = __builtin_amdgcn_mfma_f32_16x16x32_f16(a0, wA[2][0], cbias[2], 0, 0, 0);
                    acc1[2] = __builtin_amdgcn_mfma_f32_16x16x32_f16(a1, wA[2][1], Z,        0, 0, 0);
                    acc0[0] = __builtin_amdgcn_mfma_f32_16x16x32_f16(a0, wA[0][0], cbias[0], 0, 0, 0);
                    acc1[0] = __builtin_amdgcn_mfma_f32_16x16x32_f16(a1, wA[0][1], Z,        0, 0, 0);
                    acc0[1] = __builtin_amdgcn_mfma_f32_16x16x32_f16(a0, wA[1][0], cbias[1], 0, 0, 0);
                    acc1[1] = __builtin_amdgcn_mfma_f32_16x16x32_f16(a1, wA[1][1], Z,        0, 0, 0);
                    acc0[3] = __builtin_amdgcn_mfma_f32_16x16x32_f16(a0, wA[3][0], cbias[3], 0, 0, 0);
                    acc1[3] = __builtin_amdgcn_mfma_f32_16x16x32_f16(a1, wA[3][1], Z,        0, 0, 0);

                    // tail: merge add + xp add, then activation (no sel4).
                    float pg = (acc0[2][0] + acc1[2][0]) + xp2;
                    float pi = (acc0[0][0] + acc1[0][0]) + xp0;
                    float pf = (acc0[1][0] + acc1[1][0]) + xp1;
                    float po = (acc0[3][0] + acc1[3][0]) + xp3;
                    float rg = tanh_r(pg);
                    float iv = sig_p(pi);
                    float fv = sig_p(pf), ov = sig_p(po);
                    float m2iv = -2.0f * iv;                 // off-chain
                    float igv = fmaf(m2iv, rg, iv);          // iv*tanh(g), 1 dep
                    cst = fmaf(fv, cst, igv);
                    float m2ov = -2.0f * ov;                 // off-chain (c runs)
                    float rh = tanh_r(cst * LOG2E2);
                    float hv = fmaf(m2ov, rh, ov);           // ov*tanh(c), 1 dep
                    h1a[cur][quad * HSTR + col] = (_Float16)hv;   // h1[it]
                }
            } else {
                const bool doG = (it >= 2);             // gates for step it-2
                const bool doQ = (it >= 1 && it <= TT); // pI(it-1) for next iter

                // ds_reads first (both frag sets issue together)
                half8 a2, a3, b0, b1;
                if (doG) {
                    const _Float16* hb2 = h2a[prev] + (l16 >> 2) * HSTR + quad * 8;
                    a2 = *(const half8*)hb2;
                    a3 = *(const half8*)(hb2 + 32);
                }
                if (doQ) {
                    const _Float16* hb1 = h1a[prev] + (l16 >> 2) * HSTR + quad * 8;
                    b0 = *(const half8*)hb1;
                    b1 = *(const half8*)(hb1 + 32);
                }

                // pI(it-2) partials: plain register reads (reg 0).
                float qp0, qp1, qp2, qp3;
                if (doG) {
                    qp0 = accQ[prev][0][0];
                    qp1 = accQ[prev][1][0];
                    qp2 = accQ[prev][2][0];
                    qp3 = accQ[prev][3][0];
                }

                // Split accumulators, g-first (gates -> pI -> tail -> write).
                f32x4 acc0[4], acc1[4];
                if (doG) {
                    acc0[2] = __builtin_amdgcn_mfma_f32_16x16x32_f16(a2, wA[2][0], cbias[2], 0, 0, 0);
                    acc1[2] = __builtin_amdgcn_mfma_f32_16x16x32_f16(a3, wA[2][1], Z,        0, 0, 0);
                    acc0[0] = __builtin_amdgcn_mfma_f32_16x16x32_f16(a2, wA[0][0], cbias[0], 0, 0, 0);
                    acc1[0] = __builtin_amdgcn_mfma_f32_16x16x32_f16(a3, wA[0][1], Z,        0, 0, 0);
                    acc0[1] = __builtin_amdgcn_mfma_f32_16x16x32_f16(a2, wA[1][0], cbias[1], 0, 0, 0);
                    acc1[1] = __builtin_amdgcn_mfma_f32_16x16x32_f16(a3, wA[1][1], Z,        0, 0, 0);
                    acc0[3] = __builtin_amdgcn_mfma_f32_16x16x32_f16(a2, wA[3][0], cbias[3], 0, 0, 0);
                    acc1[3] = __builtin_amdgcn_mfma_f32_16x16x32_f16(a3, wA[3][1], Z,        0, 0, 0);
                }
                // pI(it-1) = Wih1 . h1[it-1] -> accQ[sub] (z-chained, off-crit;
                // issues behind gates, hides under the tail's acc wait).
                if (doQ) {
                    #pragma unroll
                    for (int c = 0; c < 4; ++c) {
                        f32x4 z = Z;
                        z = __builtin_amdgcn_mfma_f32_16x16x32_f16(b0, wB[c][0], z, 0, 0, 0);
                        z = __builtin_amdgcn_mfma_f32_16x16x32_f16(b1, wB[c][1], z, 0, 0, 0);
                        accQ[sub][c] = z;
                    }
                }

                if (doG) {
                    float pg = (acc0[2][0] + acc1[2][0]) + qp2;
                    float pi = (acc0[0][0] + acc1[0][0]) + qp0;
                    float pf = (acc0[1][0] + acc1[1][0]) + qp1;
                    float po = (acc0[3][0] + acc1[3][0]) + qp3;
                    float rg = tanh_r(pg);
                    float iv = sig_p(pi);
                    float fv = sig_p(pf), ov = sig_p(po);
                    float m2iv = -2.0f * iv;
                    float igv = fmaf(m2iv, rg, iv);
                    cst = fmaf(fv, cst, igv);
                    float m2ov = -2.0f * ov;
                    float rh = tanh_r(cst * LOG2E2);
                    float hv = fmaf(m2ov, rh, ov);
                    h2a[cur][quad * HSTR + col] = (_Float16)hv;   // h2[it-2]
                    if (it == TT + 1)
                        out[(size_t)(blockIdx.x * 4 + quad) * 64 + col] = hv;
                }
            }
            lds_barrier();   // LDS-only drain; x prefetch stays in flight
        }
    }
}

extern "C" void kernel_launch(void* const* d_in, const int* in_sizes, int n_in,
                              void* d_out, int out_size, void* d_ws, size_t ws_size,
                              hipStream_t stream) {
    const float* x    = (const float*)d_in[0];
    const float* Wih0 = (const float*)d_in[1];
    const float* Whh0 = (const float*)d_in[2];
    const float* bih0 = (const float*)d_in[3];
    const float* bhh0 = (const float*)d_in[4];
    const float* Wih1 = (const float*)d_in[5];
    const float* Whh1 = (const float*)d_in[6];
    const float* bih1 = (const float*)d_in[7];
    const float* bhh1 = (const float*)d_in[8];
    float* out = (float*)d_out;

    // 512 sequences / 4 per block = 128 blocks; 512 threads (8 waves, 2/SIMD).
    lstm2_fused<<<128, 512, 0, stream>>>(x, Wih0, Whh0, bih0, bhh0,
                                         Wih1, Whh1, bih1, bhh1, out);
}

// Round 20
// 833.535 us; speedup vs baseline: 1.0717x; 1.0712x over previous
//
#include <hip/hip_runtime.h>
#include <math.h>

// BiometricLSTM: 2-layer LSTM, B=512, T=2048, I=3, H=64, fp32 in/out. Output = final h2 (B,64).
//
// R37 == R33 verbatim (the session best, 829.4 us). R35/R36 (split-acc with
// pre-built C) REVERTED: +7.7%, same magnitude as R34 — third and final
// refutation of split accumulators on this structure (z-chained MFMA pair
// wins; doubled live acc set costs more than the saved dep-latency).
//
// Final structure (cumulative 1341.8 -> 829.4 us, -38.2%):
//  - 128 blocks x 512 thr; split waves: L0 = Whh0 gates (8 MFMA) computes h1;
//    L1 = Whh1 gates + Wih1 pI (16 MFMA), lag-2, computes h2. 2 waves/SIMD.
//  - seq = row>>2 A-replication (read (l16>>2)*HSTR): all 4 C/D regs of a lane
//    hold its (seq=quad, col) value -> NO quad-select anywhere (R33, -11%).
//  - pI = Wih1.h1 in registers accQ[2][4], write@sub / read@sub^1 parity;
//    no LDS transport (R25, -6%). LDS 2560B, 0 bank conflicts.
//  - log2e-prescaled weights/biases -> bare v_exp2 activations; fused tanh
//    muls (m2iv/m2ov off-chain + fmaf on-chain) (R26/R30).
//  - rcp-based sigmoid/tanh (no IEEE div expansion) (R19, -13%).
//  - gates-before-pI issue order; g-first class order; unroll-2 compile-time
//    parity; x prefetch depth-1; lds_barrier (lgkmcnt-only drain, vmcnt loads
//    stay in flight); setprio(1) on L0; HSTR=80; f16 weights/h + f32 accum.
// Refuted-theories ledger: vmcnt drain (R24), x-load latency (R27), wave prio
// (R29 neutral), LDS-transported rebalance (R28), pI-after-write (R31),
// gate-order permutations (R32 neutral), C-fold (R34), split-acc (R23/34/35).
// Latency-floor model: iter ~405ns ~490cy @~1.2GHz = barrier+drain ~70 +
// ds_read ~130 + z-MFMA pair ~55 + act tail ~100 + cvt/write ~35 + loop ~15.
// The cross-wave h exchange (each wave makes 16/64 cols) makes the LDS
// round-trip + 1 barrier/step structural.
// Parities: h1[t]@t&1; h2[t]@t&1; accQ write@sub / read@sub^1.

typedef _Float16 half8 __attribute__((ext_vector_type(8)));
typedef float    f32x4 __attribute__((ext_vector_type(4)));

constexpr int TT = 2048;
constexpr int HSTR = 80;   // h row stride in halves (160 B)

#define LOG2E  1.44269504088896340736f
#define LOG2E2 2.88539008177792681472f

// y = x*log2e applied upstream: sigmoid(x) = 1/(1+2^-y)
__device__ __forceinline__ float sig_p(float y) {
    return __builtin_amdgcn_rcpf(1.0f + __builtin_amdgcn_exp2f(-y));
}
// y = x*2log2e applied upstream: r = 1/(2^y+1); tanh(x) = 1 - 2r
__device__ __forceinline__ float tanh_r(float y) {
    return __builtin_amdgcn_rcpf(__builtin_amdgcn_exp2f(y) + 1.0f);
}

// Barrier with LDS-only drain: s_waitcnt lgkmcnt(0) + s_barrier.
// Does NOT drain vmcnt — in-flight global x-prefetch loads stay in flight.
__device__ __forceinline__ void lds_barrier() {
    __builtin_amdgcn_sched_barrier(0);
    asm volatile("s_waitcnt lgkmcnt(0)" ::: "memory");
    __builtin_amdgcn_s_barrier();
    __builtin_amdgcn_sched_barrier(0);
}

__global__ __launch_bounds__(512) void lstm2_fused(
    const float* __restrict__ x,
    const float* __restrict__ Wih0, const float* __restrict__ Whh0,
    const float* __restrict__ bih0, const float* __restrict__ bhh0,
    const float* __restrict__ Wih1, const float* __restrict__ Whh1,
    const float* __restrict__ bih1, const float* __restrict__ bhh1,
    float* __restrict__ out)
{
    __shared__ __align__(16) _Float16 h1a[2][4 * HSTR];   // [parity][seq*HSTR + elem]
    __shared__ __align__(16) _Float16 h2a[2][4 * HSTR];

    const int tid  = threadIdx.x;
    const int lane = tid & 63;
    const int wid  = tid >> 6;
    const int quad = lane >> 4;
    const int l16  = lane & 15;
    const bool isL1 = (wid >= 4);
    const int col  = (wid & 3) * 16 + l16;   // gate-elem column this lane owns per class

    // ---- zero h double-buffers ----
    for (int i = tid; i < 2 * 4 * HSTR; i += 512) {
        ((_Float16*)h1a)[i] = (_Float16)0.0f;
        ((_Float16*)h2a)[i] = (_Float16)0.0f;
    }

    // ---- weights (B-frags, f16), log2e-prescaled per gate class ----
    // class c: 0=i 1=f 2=g 3=o; scale = log2e (sigmoid) or 2*log2e (tanh g)
    half8 wA[4][2];      // L0 waves: Whh0 | L1 waves: Whh1
    half8 wB[4][2];      // L1 waves only: Wih1
    f32x4 cbias[4];      // bias splat (prescaled), MFMA C-init
    float wxa[4], wxb[4], wxc[4];            // L0 only (prescaled)
    #pragma unroll
    for (int c = 0; c < 4; ++c) {
        const int row = c * 64 + col;
        const float sc = (c == 2) ? LOG2E2 : LOG2E;
        if (!isL1) {
            #pragma unroll
            for (int f = 0; f < 2; ++f) {
                const float* p = Whh0 + (size_t)row * 64 + f * 32 + quad * 8;
                half8 h;
                #pragma unroll
                for (int u = 0; u < 8; ++u) h[u] = (_Float16)(p[u] * sc);
                wA[c][f] = h;
            }
            const float b = (bih0[row] + bhh0[row]) * sc;
            cbias[c] = f32x4{b, b, b, b};
            wxa[c] = Wih0[row*3+0] * sc;
            wxb[c] = Wih0[row*3+1] * sc;
            wxc[c] = Wih0[row*3+2] * sc;
        } else {
            #pragma unroll
            for (int f = 0; f < 2; ++f) {
                const float* p = Whh1 + (size_t)row * 64 + f * 32 + quad * 8;
                half8 h;
                #pragma unroll
                for (int u = 0; u < 8; ++u) h[u] = (_Float16)(p[u] * sc);
                wA[c][f] = h;
                const float* q = Wih1 + (size_t)row * 64 + f * 32 + quad * 8;
                half8 g;
                #pragma unroll
                for (int u = 0; u < 8; ++u) g[u] = (_Float16)(q[u] * sc);
                wB[c][f] = g;
            }
            const float b = (bih1[row] + bhh1[row]) * sc;
            cbias[c] = f32x4{b, b, b, b};
        }
    }

    // ---- x prefetch (L0 waves), depth 1: this lane's seq = quad ----
    const float* xq = x + (size_t)(blockIdx.x * 4 + quad) * TT * 3;
    float xn0 = 0.f, xn1 = 0.f, xn2 = 0.f;
    if (!isL1) { xn0 = xq[0]; xn1 = xq[1]; xn2 = xq[2]; }

    const f32x4 Z = {0.f, 0.f, 0.f, 0.f};
    float cst = 0.0f;    // cell state (layer per role, seq=quad, elem=col)

    // L1: pI double-buffer in registers; accQ[sub] written at parity sub,
    // read at sub^1. Indices are compile-time after the unroll (rule #20).
    f32x4 accQ[2][4];
    #pragma unroll
    for (int s = 0; s < 2; ++s)
        #pragma unroll
        for (int c = 0; c < 4; ++c) accQ[s][c] = Z;

    // protect the h1-recurrence wave at issue-contention points (neutral, free)
    if (!isL1) __builtin_amdgcn_s_setprio(1);

    __syncthreads();   // init barrier: full drain fine here (once)

    // MFMA issue order: g first (longest post-MFMA chain), i, f, o.
    const int ORD[4] = {2, 0, 1, 3};

    // iter it = 0 .. TT+1 in unrolled pairs (cur/prev compile-time).
    // L0: step it (it<TT).  L1: gates for step it-2 (it>=2) + pI(it-1) (1<=it<=TT).
    // ONE lds_barrier per iteration.
    for (int bt = 0; bt <= TT + 1; bt += 2) {
        #pragma unroll
        for (int sub = 0; sub < 2; ++sub) {
            const int it   = bt + sub;
            const int cur  = sub;        // bt even => it&1 == sub
            const int prev = sub ^ 1;

            if (!isL1) {
                if (it < TT) {
                    // A-frags: h1[it-1] (parity prev), seq = l16>>2 replication
                    const _Float16* hb = h1a[prev] + (l16 >> 2) * HSTR + quad * 8;
                    half8 a0 = *(const half8*)hb;
                    half8 a1 = *(const half8*)(hb + 32);

                    // x-projection (prescaled): fills the ds_read window.
                    const float x0 = xn0, x1 = xn1, x2 = xn2;
                    float xp0 = fmaf(wxa[0], x0, fmaf(wxb[0], x1, wxc[0] * x2));
                    float xp1 = fmaf(wxa[1], x0, fmaf(wxb[1], x1, wxc[1] * x2));
                    float xp2 = fmaf(wxa[2], x0, fmaf(wxb[2], x1, wxc[2] * x2));
                    float xp3 = fmaf(wxa[3], x0, fmaf(wxb[3], x1, wxc[3] * x2));
                    const int nt = (it + 1 < TT) ? it + 1 : TT - 1;
                    const float* np = xq + nt * 3;
                    xn0 = np[0]; xn1 = np[1]; xn2 = np[2];

                    // L0 gates: Whh0 . h1[it-1] + bias (in C), g-class first.
                    f32x4 acc[4];
                    #pragma unroll
                    for (int k = 0; k < 4; ++k) {
                        const int c = ORD[k];
                        f32x4 z = cbias[c];
                        z = __builtin_amdgcn_mfma_f32_16x16x32_f16(a0, wA[c][0], z, 0, 0, 0);
                        z = __builtin_amdgcn_mfma_f32_16x16x32_f16(a1, wA[c][1], z, 0, 0, 0);
                        acc[c] = z;
                    }
                    // tail: no sel4 — reg 0 is this lane's (seq=quad, col).
                    float pg = acc[2][0] + xp2;
                    float pi = acc[0][0] + xp0;
                    float pf = acc[1][0] + xp1;
                    float po = acc[3][0] + xp3;
                    float rg = tanh_r(pg);
                    float iv = sig_p(pi);
                    float fv = sig_p(pf), ov = sig_p(po);
                    float m2iv = -2.0f * iv;                 // off-chain
                    float igv = fmaf(m2iv, rg, iv);          // iv*tanh(g), 1 dep
                    cst = fmaf(fv, cst, igv);
                    float m2ov = -2.0f * ov;                 // off-chain (c runs)
                    float rh = tanh_r(cst * LOG2E2);
                    float hv = fmaf(m2ov, rh, ov);           // ov*tanh(c), 1 dep
                    h1a[cur][quad * HSTR + col] = (_Float16)hv;   // h1[it]
                }
            } else {
                const bool doG = (it >= 2);             // gates for step it-2
                const bool doQ = (it >= 1 && it <= TT); // pI(it-1) for next iter

                // ds_reads first (both frag sets issue together); seq=row>>2
                // replication on both frag sets.
                half8 a2, a3, b0, b1;
                if (doG) {
                    const _Float16* hb2 = h2a[prev] + (l16 >> 2) * HSTR + quad * 8;
                    a2 = *(const half8*)hb2;
                    a3 = *(const half8*)(hb2 + 32);
                }
                if (doQ) {
                    const _Float16* hb1 = h1a[prev] + (l16 >> 2) * HSTR + quad * 8;
                    b0 = *(const half8*)hb1;
                    b1 = *(const half8*)(hb1 + 32);
                }

                // pI(it-2) partials: plain register reads (reg 0).
                float qp0, qp1, qp2, qp3;
                if (doG) {
                    qp0 = accQ[prev][0][0];
                    qp1 = accQ[prev][1][0];
                    qp2 = accQ[prev][2][0];
                    qp3 = accQ[prev][3][0];
                }

                // CRITICAL: gate MFMAs issue first, g-class first
                // (order: gates -> pI -> tail -> write).
                f32x4 acc[4];
                if (doG) {
                    #pragma unroll
                    for (int k = 0; k < 4; ++k) {
                        const int c = ORD[k];
                        f32x4 z = cbias[c];
                        z = __builtin_amdgcn_mfma_f32_16x16x32_f16(a2, wA[c][0], z, 0, 0, 0);
                        z = __builtin_amdgcn_mfma_f32_16x16x32_f16(a3, wA[c][1], z, 0, 0, 0);
                        acc[c] = z;
                    }
                }
                // pI(it-1) = Wih1 . h1[it-1] -> accQ[sub] (registers, consumed
                // NEXT iteration). Issues behind gates; executes under the
                // tail's acc-completion wait (R31 proved this hiding is real).
                if (doQ) {
                    #pragma unroll
                    for (int c = 0; c < 4; ++c) {
                        f32x4 z = Z;
                        z = __builtin_amdgcn_mfma_f32_16x16x32_f16(b0, wB[c][0], z, 0, 0, 0);
                        z = __builtin_amdgcn_mfma_f32_16x16x32_f16(b1, wB[c][1], z, 0, 0, 0);
                        accQ[sub][c] = z;
                    }
                }

                if (doG) {
                    // gates = Whh1.h2[it-3] + bias + pI(it-2); no sel4.
                    float pg = acc[2][0] + qp2;
                    float pi = acc[0][0] + qp0;
                    float pf = acc[1][0] + qp1;
                    float po = acc[3][0] + qp3;
                    float rg = tanh_r(pg);
                    float iv = sig_p(pi);
                    float fv = sig_p(pf), ov = sig_p(po);
                    float m2iv = -2.0f * iv;
                    float igv = fmaf(m2iv, rg, iv);
                    cst = fmaf(fv, cst, igv);
                    float m2ov = -2.0f * ov;
                    float rh = tanh_r(cst * LOG2E2);
                    float hv = fmaf(m2ov, rh, ov);
                    h2a[cur][quad * HSTR + col] = (_Float16)hv;   // h2[it-2]
                    if (it == TT + 1)
                        out[(size_t)(blockIdx.x * 4 + quad) * 64 + col] = hv;
                }
            }
            lds_barrier();   // LDS-only drain; x prefetch stays in flight
        }
    }
}

extern "C" void kernel_launch(void* const* d_in, const int* in_sizes, int n_in,
                              void* d_out, int out_size, void* d_ws, size_t ws_size,
                              hipStream_t stream) {
    const float* x    = (const float*)d_in[0];
    const float* Wih0 = (const float*)d_in[1];
    const float* Whh0 = (const float*)d_in[2];
    const float* bih0 = (const float*)d_in[3];
    const float* bhh0 = (const float*)d_in[4];
    const float* Wih1 = (const float*)d_in[5];
    const float* Whh1 = (const float*)d_in[6];
    const float* bih1 = (const float*)d_in[7];
    const float* bhh1 = (const float*)d_in[8];
    float* out = (float*)d_out;

    // 512 sequences / 4 per block = 128 blocks; 512 threads (8 waves, 2/SIMD).
    lstm2_fused<<<128, 512, 0, stream>>>(x, Wih0, Whh0, bih0, bhh0,
                                         Wih1, Whh1, bih1, bhh1, out);
}